// Round 1
// baseline (237.950 us; speedup 1.0000x reference)
//
#include <hip/hip_runtime.h>
#include <hip/hip_bf16.h>

typedef __attribute__((ext_vector_type(8))) short short8;
typedef __attribute__((ext_vector_type(4))) float floatx4;

#define NN 4096
#define BB 4

// round-to-nearest-even f32 -> bf16 bits
static __device__ __forceinline__ unsigned f2bf(float x) {
    union { float f; unsigned u; } v; v.f = x;
    unsigned r = v.u + 0x7fffu + ((v.u >> 16) & 1u);
    return r >> 16;
}

// ---------------- Kernel A: H = X@W1 (store H^T bf16), l = H@aL, r = H@aR ----
__global__ void prep_kernel(const float* __restrict__ X,
                            const float* __restrict__ W1,
                            const float* __restrict__ alpha,
                            unsigned short* __restrict__ Ht,   // [b*64+c][4096] bf16
                            float* __restrict__ lv_out,        // [b*4096+n]
                            float* __restrict__ rv_out) {
    __shared__ float W1s[64][65];
    __shared__ float Bs[64][65];     // X tile, then reused as H^T tile
    const int t = threadIdx.x;
    const int row0 = blockIdx.x * 64;        // flattened b*N + n
    const int b = row0 >> 12;
    const int n0 = row0 & (NN - 1);
    const int c = t & 63;
    const int rquad = t >> 6;

    #pragma unroll
    for (int s2 = 0; s2 < 16; ++s2) {
        int idx = t + 256 * s2;
        int rr = idx >> 6, k = idx & 63;
        W1s[rr][k] = W1[idx];
        Bs[rr][k]  = X[(size_t)row0 * 64 + idx];
    }
    __syncthreads();

    const float aL = alpha[c], aR = alpha[64 + c];
    float h[16];
    #pragma unroll
    for (int rr = 0; rr < 16; ++rr) {
        const int rl = rr * 4 + rquad;       // wave-uniform row
        float acc = 0.f;
        #pragma unroll
        for (int k = 0; k < 64; ++k) acc += Bs[rl][k] * W1s[k][c];
        h[rr] = acc;
        float pl = acc * aL, pr = acc * aR;
        #pragma unroll
        for (int off = 32; off > 0; off >>= 1) {
            pl += __shfl_xor(pl, off, 64);
            pr += __shfl_xor(pr, off, 64);
        }
        if (c == 0) { lv_out[row0 + rl] = pl; rv_out[row0 + rl] = pr; }
    }
    __syncthreads();
    // transpose through LDS: Bs[c][row_local] = h
    #pragma unroll
    for (int rr = 0; rr < 16; ++rr) Bs[c][rr * 4 + rquad] = h[rr];
    __syncthreads();
    // coalesced bf16 pair stores of Ht rows
    unsigned* Hu = (unsigned*)Ht;
    #pragma unroll
    for (int it2 = 0; it2 < 8; ++it2) {
        int c2 = (t >> 5) + it2 * 8;
        int np = t & 31;
        unsigned lo = f2bf(Bs[c2][2 * np]);
        unsigned hi = f2bf(Bs[c2][2 * np + 1]);
        Hu[((((size_t)(b * 64 + c2) << 12) + n0) >> 1) + np] = lo | (hi << 16);
    }
}

// ---------------- Kernel B: num[b,i,c] = sum_j e_ij*H[j,c]; den[b,i] = sum_j e_ij
__global__ void attn_kernel(const float* __restrict__ A,
                            const unsigned short* __restrict__ Ht,
                            const float* __restrict__ lv,
                            const float* __restrict__ rv,
                            float* __restrict__ num,   // [b*4096+i][64]
                            float* __restrict__ den) { // [b*4096+i]
    __shared__ __align__(16) float rs[1024];
    const int bid = blockIdx.x;
    const int it = bid & 63;
    const int b  = (bid >> 6) & 3;
    const int js = bid >> 8;
    const int i0 = it * 64;
    const int jbase = js * 1024;
    const int t = threadIdx.x;
    const int w = t >> 6, lane = t & 63;
    const int m = lane & 15, q = lane >> 4;
    const int i = i0 + w * 16 + m;          // A-fragment row this lane generates

    #pragma unroll
    for (int s2 = 0; s2 < 4; ++s2)
        rs[t + 256 * s2] = rv[b * NN + jbase + t + 256 * s2];
    __syncthreads();

    const float li = lv[b * NN + i];
    const float* adjRow = A + (size_t)i * NN;

    floatx4 acc0 = {0,0,0,0}, acc1 = {0,0,0,0}, acc2 = {0,0,0,0}, acc3 = {0,0,0,0};
    float denp = 0.f;

    for (int jj0 = 0; jj0 < 1024; jj0 += 32) {
        const int j0 = jbase + jj0;
        const int jq = j0 + q * 8;
        float4 a0 = *(const float4*)(adjRow + jq);
        float4 a1 = *(const float4*)(adjRow + jq + 4);
        float4 r0 = *(const float4*)(&rs[jj0 + q * 8]);
        float4 r1 = *(const float4*)(&rs[jj0 + q * 8 + 4]);
        float av[8]  = {a0.x, a0.y, a0.z, a0.w, a1.x, a1.y, a1.z, a1.w};
        float rvv[8] = {r0.x, r0.y, r0.z, r0.w, r1.x, r1.y, r1.z, r1.w};
        short8 afr;
        #pragma unroll
        for (int e = 0; e < 8; ++e) {
            float aa = (jq + e == i) ? 1.0f : av[e];   // diag forced to 1.0
            float s  = li * rvv[e];
            s = fmaxf(s, 0.01f * s);                   // leaky_relu slope 0.01
            float ev = __expf(s) * aa;
            denp += ev;
            afr[e] = (short)f2bf(ev);
        }
        const unsigned short* hb = Ht + (((size_t)(b * 64 + m)) << 12) + jq;
        short8 b0 = *(const short8*)(hb);
        short8 b1 = *(const short8*)(hb + ((size_t)16 << 12));
        short8 b2 = *(const short8*)(hb + ((size_t)32 << 12));
        short8 b3 = *(const short8*)(hb + ((size_t)48 << 12));
        acc0 = __builtin_amdgcn_mfma_f32_16x16x32_bf16(afr, b0, acc0, 0, 0, 0);
        acc1 = __builtin_amdgcn_mfma_f32_16x16x32_bf16(afr, b1, acc1, 0, 0, 0);
        acc2 = __builtin_amdgcn_mfma_f32_16x16x32_bf16(afr, b2, acc2, 0, 0, 0);
        acc3 = __builtin_amdgcn_mfma_f32_16x16x32_bf16(afr, b3, acc3, 0, 0, 0);
    }

    // denominator: rows live on lanes {m, m+16, m+32, m+48}
    denp += __shfl_xor(denp, 16, 64);
    denp += __shfl_xor(denp, 32, 64);
    if (lane < 16) atomicAdd(&den[b * NN + i0 + w * 16 + lane], denp);

    // C/D layout: col = lane&15, row = (lane>>4)*4 + reg  (m89-verified)
    #pragma unroll
    for (int nt = 0; nt < 4; ++nt) {
        floatx4 acc = nt == 0 ? acc0 : nt == 1 ? acc1 : nt == 2 ? acc2 : acc3;
        #pragma unroll
        for (int rg = 0; rg < 4; ++rg) {
            int ii = i0 + w * 16 + q * 4 + rg;
            int ccol = nt * 16 + m;
            atomicAdd(&num[((size_t)(b * NN + ii) << 6) + ccol], acc[rg]);
        }
    }
}

// ---------------- Kernel C: out = (num/den) @ W2 ----------------------------
__global__ void out_kernel(const float* __restrict__ num,
                           const float* __restrict__ den,
                           const float* __restrict__ W2,
                           float* __restrict__ out) {
    __shared__ float W2s[64][65];
    __shared__ float Ns[64][65];
    const int t = threadIdx.x;
    const int row0 = blockIdx.x * 64;
    const int c = t & 63, rquad = t >> 6;
    #pragma unroll
    for (int s2 = 0; s2 < 16; ++s2) {
        int idx = t + 256 * s2;
        int rr = idx >> 6, k = idx & 63;
        W2s[rr][k] = W2[idx];
        Ns[rr][k]  = num[(size_t)row0 * 64 + idx] / den[row0 + rr];
    }
    __syncthreads();
    #pragma unroll
    for (int rr = 0; rr < 16; ++rr) {
        const int rl = rr * 4 + rquad;
        float acc = 0.f;
        #pragma unroll
        for (int k = 0; k < 64; ++k) acc += Ns[rl][k] * W2s[k][c];
        out[(size_t)(row0 + rl) * 64 + c] = acc;
    }
}

extern "C" void kernel_launch(void* const* d_in, const int* in_sizes, int n_in,
                              void* d_out, int out_size, void* d_ws, size_t ws_size,
                              hipStream_t stream) {
    const float* X     = (const float*)d_in[0];
    const float* A     = (const float*)d_in[1];
    const float* W1    = (const float*)d_in[2];
    const float* W2    = (const float*)d_in[3];
    const float* alpha = (const float*)d_in[4];
    float* out = (float*)d_out;

    char* ws = (char*)d_ws;
    unsigned short* Ht = (unsigned short*)(ws);                    // 2 MiB
    float* lv  = (float*)(ws + 2097152);                           // 64 KiB
    float* rv  = (float*)(ws + 2097152 + 65536);                   // 64 KiB
    float* num = (float*)(ws + 2097152 + 131072);                  // 4 MiB
    float* den = (float*)(ws + 2097152 + 131072 + 4194304);        // 64 KiB

    hipMemsetAsync(num, 0, 4194304 + 65536, stream);               // num + den
    prep_kernel<<<256, 256, 0, stream>>>(X, W1, alpha, Ht, lv, rv);
    attn_kernel<<<1024, 256, 0, stream>>>(A, Ht, lv, rv, num, den);
    out_kernel<<<256, 256, 0, stream>>>(num, den, W2, out);
}